// Round 1
// baseline (150763.403 us; speedup 1.0000x reference)
//
#include <hip/hip_runtime.h>
#include <hip/hip_cooperative_groups.h>
#include <cmath>

namespace cg = cooperative_groups;

// Problem dims (from reference setup_inputs)
#define T_STEPS 2048
#define BATCH   32
#define NN      2048
#define BN      (BATCH * NN)

// Launch shape: 512 blocks x 256 threads, cooperative (2 blocks/CU on 256 CUs)
#define NBLK     512
#define NTHREADS 256
#define NJ       4              // output columns per block (NBLK*NJ == NN)
#define KSEC     4              // K-split sections per block
#define KLEN     (NN / KSEC)    // 512

__global__ __launch_bounds__(NTHREADS)
void lif_persistent(const float* __restrict__ x_in,
                    const float* __restrict__ v0,
                    const float* __restrict__ s0,
                    const float* __restrict__ w,
                    const float* __restrict__ E_L,
                    const float* __restrict__ tau_m,
                    const float* __restrict__ tau_s,
                    const int*   __restrict__ ntypes,
                    float*       __restrict__ out,
                    float*       __restrict__ ws)
{
    cg::grid_group grid = cg::this_grid();

    // W_eff^T slice for this block's 4 columns: wT[jl][i], 32 KB.
    // Row stride 2048 floats => ds_read_b128 across the 2 j-halves is a
    // 2-way bank alias, which is free on gfx950 (m136). +2 KB reduce buffer.
    __shared__ float wT[NJ][NN];
    __shared__ float red[KSEC][BATCH][NJ];

    float* sbuf0 = ws;            // s state, ping
    float* sbuf1 = ws + BN;       // s state, pong

    const int blk = blockIdx.x;
    const int tid = threadIdx.x;
    const int j0  = blk * NJ;

    // ---- one-time: preload W_eff^T slice into LDS (W never touched again) ----
    for (int i = tid; i < NN; i += NTHREADS) {
        const float4 wv = *reinterpret_cast<const float4*>(w + (size_t)i * NN + j0);
        const float nt = (float)ntypes[i];
        float w0 = wv.x * nt, w1 = wv.y * nt, w2 = wv.z * nt, w3 = wv.w * nt;
        if (i == j0    ) w0 = 0.0f;   // self-recurrence mask (diag = 0)
        if (i == j0 + 1) w1 = 0.0f;
        if (i == j0 + 2) w2 = 0.0f;
        if (i == j0 + 3) w3 = 0.0f;
        wT[0][i] = w0; wT[1][i] = w1; wT[2][i] = w2; wT[3][i] = w3;
    }

    // ---- one-time: init s state (v lives purely in registers below) ----
    for (int idx = blk * NTHREADS + tid; idx < BN; idx += NBLK * NTHREADS) {
        sbuf0[idx] = s0[idx];
    }

    // GEMM mapping: 4 waves = 4 K-sections; within a wave, lane -> (b, j-half)
    const int ksec = tid >> 6;          // 0..3
    const int lane = tid & 63;
    const int b    = lane >> 1;         // 0..31
    const int js   = (lane & 1) * 2;    // 0 or 2 (two adjacent j's per thread)

    // Phase-2 mapping: threads 0..127 each own one (batch, neuron) state cell
    const bool p2 = (tid < BATCH * NJ);
    const int  b2 = tid >> 2;
    const int  jl = tid & 3;
    const int  jg = j0 + jl;
    float el = 0.f, tm = 1.f, ts = 1.f, nR = 0.f, dvmax = 1.f;
    float vreg = 0.f, sreg = 0.f;
    size_t idx2 = 0;
    if (p2) {
        el    = E_L[jg];
        tm    = tau_m[jg];
        ts    = tau_s[jg];
        nR    = (30.0f - el) * 1.1f;   // (THRESH - E_L) * R_CONST
        dvmax = 30.0f - el;            // THRESH - E_L
        idx2  = (size_t)b2 * NN + jg;
        vreg  = v0[idx2];              // v state: register-resident whole run
        sreg  = s0[idx2];              // own copy of s state
    }

    grid.sync();   // LDS + s0 visible everywhere

    for (int t = 0; t < T_STEPS; ++t) {
        const float* __restrict__ sread  = (t & 1) ? sbuf1 : sbuf0;
        float*       __restrict__ swrite = (t & 1) ? sbuf0 : sbuf1;

        // Prefetch this step's x early; consumed after the GEMM (latency hidden)
        float xv = 0.0f;
        if (p2) xv = __builtin_nontemporal_load(x_in + (size_t)t * BN + idx2);

        // ---- phase 1: partial dot products, K-section ksec ----
        float acc0 = 0.0f, acc1 = 0.0f;
        {
            const float* __restrict__ srow = sread + (size_t)b * NN;
            const int i0 = ksec * KLEN;
            #pragma unroll 4
            for (int i = i0; i < i0 + KLEN; i += 4) {
                const float4 sv = *reinterpret_cast<const float4*>(srow + i);
                const float4 wa = *reinterpret_cast<const float4*>(&wT[js][i]);
                const float4 wb = *reinterpret_cast<const float4*>(&wT[js + 1][i]);
                acc0 = fmaf(sv.x, wa.x, acc0);
                acc1 = fmaf(sv.x, wb.x, acc1);
                acc0 = fmaf(sv.y, wa.y, acc0);
                acc1 = fmaf(sv.y, wb.y, acc1);
                acc0 = fmaf(sv.z, wa.z, acc0);
                acc1 = fmaf(sv.z, wb.z, acc1);
                acc0 = fmaf(sv.w, wa.w, acc0);
                acc1 = fmaf(sv.w, wb.w, acc1);
            }
        }
        red[ksec][b][js]     = acc0;
        red[ksec][b][js + 1] = acc1;
        __syncthreads();

        // ---- phase 2: K-reduce + LIF update + output (threads 0..127) ----
        if (p2) {
            const float dot = red[0][b2][jl] + red[1][b2][jl]
                            + red[2][b2][jl] + red[3][b2][jl];
            const float I   = dot + 1.75f * xv;          // INPUT_GAIN * x
            const float dv  = ((el - vreg) + I * nR) / tm;
            const float vn  = vreg + dv;
            float gating = vn / 30.0f;
            gating = fminf(fmaxf(gating, 0.0f), 1.0f);
            float cdv = dv / dvmax;
            cdv = fminf(fmaxf(cdv, 0.0f), 1.0f);
            const float snew = sreg + (gating * cdv - sreg) / ts;
            swrite[idx2] = snew;
            sreg = snew;
            vreg = (vn >= 30.0f) ? el : vn;              // spike reset
            const float sig = 1.0f / (1.0f + expf(30.0f - vn));
            __builtin_nontemporal_store(sig, out + (size_t)t * BN + idx2);
        }

        grid.sync();   // publish swrite to all blocks (fence inside sync)
    }
}

extern "C" void kernel_launch(void* const* d_in, const int* in_sizes, int n_in,
                              void* d_out, int out_size, void* d_ws, size_t ws_size,
                              hipStream_t stream) {
    (void)in_sizes; (void)n_in; (void)out_size; (void)ws_size;
    const float* x_in   = (const float*)d_in[0];
    const float* v0     = (const float*)d_in[1];
    const float* s0     = (const float*)d_in[2];
    const float* w      = (const float*)d_in[3];
    const float* E_L    = (const float*)d_in[4];
    const float* tau_m  = (const float*)d_in[5];
    const float* tau_s  = (const float*)d_in[6];
    const int*   ntypes = (const int*)d_in[7];
    float* out = (float*)d_out;
    float* ws  = (float*)d_ws;   // needs 2*BN floats = 512 KB

    void* args[] = { (void*)&x_in, (void*)&v0, (void*)&s0, (void*)&w,
                     (void*)&E_L, (void*)&tau_m, (void*)&tau_s, (void*)&ntypes,
                     (void*)&out, (void*)&ws };
    hipLaunchCooperativeKernel((const void*)lif_persistent,
                               dim3(NBLK), dim3(NTHREADS), args, 0, stream);
}